// Round 2
// baseline (75.148 us; speedup 1.0000x reference)
//
#include <hip/hip_runtime.h>

#define LAMB_COORD 5.0f
#define LAMB_NOOBJ 0.5f
#define GEPS 1e-7f

// gt/pred: (B=16384, C=30, H=7, W=7) fp32. Per b: 30 ch * 49 cells = 1470 floats.
// Block = 256 threads stages NB=4 consecutive b's (2 x 5880 floats = 47 KB LDS)
// with float4 loads, then one thread per cell (196 cells) computes from LDS.
// NB=4 keeps the group base 16B-aligned (4*1470*4 = 23520 % 16 == 0).

#define NB   4
#define FPB  1470
#define FPG  (NB * FPB)       // 5880 floats per group per input
#define NV   (FPG / 4)        // 1470 float4 per input

__global__ __launch_bounds__(256) void yolo_loss_kernel(
        const float* __restrict__ gt, const float* __restrict__ pred,
        float* __restrict__ out, int ngroups) {
    __shared__ float lg[FPG];
    __shared__ float lp[FPG];

    const int group = blockIdx.x;
    if (group >= ngroups) return;
    const int tid = threadIdx.x;

    const float4* __restrict__ gsrc = (const float4*)(gt   + (size_t)group * FPG);
    const float4* __restrict__ psrc = (const float4*)(pred + (size_t)group * FPG);

    // ---- Stage: issue all global loads up front (named regs, fully unrolled) ----
    float4 vg[6], vp[6];
    #pragma unroll
    for (int k = 0; k < 6; ++k) {
        int i = tid + k * 256;
        int ii = (i < NV) ? i : 0;       // predicate via safe index; extra loads hit cache
        vg[k] = gsrc[ii];
        vp[k] = psrc[ii];
    }
    #pragma unroll
    for (int k = 0; k < 6; ++k) {
        int i = tid + k * 256;
        if (i < NV) {
            ((float4*)lg)[i] = vg[k];
            ((float4*)lp)[i] = vp[k];
        }
    }
    __syncthreads();

    // ---- Compute: one thread per cell ----
    float s = 0.0f;
    if (tid < NB * 49) {
        const int bb = tid / 49;
        const int hw = tid - bb * 49;
        const float* __restrict__ g = lg + bb * FPB + hw;
        const float* __restrict__ p = lp + bb * FPB + hw;

        float gch[10], pch[10];
        #pragma unroll
        for (int c = 0; c < 10; ++c) {
            gch[c] = g[c * 49];
            pch[c] = p[c * 49];
        }

        // GIoU(gt box, pred box k) for k=0 (ch 0..3) and k=1 (ch 5..8)
        const float gx1 = gch[0], gy1 = gch[1];
        const float gx2 = gch[0] + gch[2], gy2 = gch[1] + gch[3];
        const float ga  = (gx2 - gx1) * (gy2 - gy1);

        float l[2];
        #pragma unroll
        for (int k = 0; k < 2; ++k) {
            const int o = k * 5;
            float px1 = pch[o + 0], py1 = pch[o + 1];
            float px2 = px1 + pch[o + 2], py2 = py1 + pch[o + 3];
            float ix1 = fmaxf(gx1, px1), iy1 = fmaxf(gy1, py1);
            float ix2 = fminf(gx2, px2), iy2 = fminf(gy2, py2);
            float inter = fmaxf(ix2 - ix1, 0.0f) * fmaxf(iy2 - iy1, 0.0f);
            float pa  = (px2 - px1) * (py2 - py1);
            float uni = ga + pa - inter;
            float iou = inter / (uni + GEPS);
            float cx1 = fminf(gx1, px1), cy1 = fminf(gy1, py1);
            float cx2 = fmaxf(gx2, px2), cy2 = fmaxf(gy2, py2);
            float enc = (cx2 - cx1) * (cy2 - cy1);
            l[k] = 1.0f - (iou - (enc - uni) / (enc + GEPS));
        }

        // jnp.argmax first-max tie-break: arg = 1 iff l2 > l1
        float r0, r1;
        if (l[1] > l[0]) { r0 = 0.0f;   r1 = gch[9]; }
        else             { r0 = gch[4]; r1 = 0.0f;   }
        const float appears = fmaxf(r0, r1);

        float d;
        d = gch[0] - pch[0]; s += d * d * r0 * LAMB_COORD;
        d = gch[1] - pch[1]; s += d * d * r0 * LAMB_COORD;
        d = gch[5] - pch[5]; s += d * d * r1 * LAMB_COORD;
        d = gch[6] - pch[6]; s += d * d * r1 * LAMB_COORD;
        d = sqrtf(gch[2]) - sqrtf(pch[2]); s += d * d * r0 * LAMB_COORD;
        d = sqrtf(gch[3]) - sqrtf(pch[3]); s += d * d * r0 * LAMB_COORD;
        d = sqrtf(gch[7]) - sqrtf(pch[7]); s += d * d * r1 * LAMB_COORD;
        d = sqrtf(gch[8]) - sqrtf(pch[8]); s += d * d * r1 * LAMB_COORD;
        d = gch[4] - pch[4]; { float d2 = d * d; s += d2 * r0 + d2 * (1.0f - r0) * LAMB_NOOBJ; }
        d = gch[9] - pch[9]; { float d2 = d * d; s += d2 * r1 + d2 * (1.0f - r1) * LAMB_NOOBJ; }

        float cls = 0.0f;
        #pragma unroll
        for (int c = 10; c < 30; ++c) {
            float dc = g[c * 49] - p[c * 49];
            cls += dc * dc;
        }
        s += cls * appears;
    }

    // ---- Reduce: 64-lane wave shuffle -> LDS -> one atomic per block ----
    #pragma unroll
    for (int off = 32; off > 0; off >>= 1)
        s += __shfl_down(s, off, 64);

    __shared__ float wsum[4];
    const int lane = tid & 63;
    const int wid  = tid >> 6;
    if (lane == 0) wsum[wid] = s;
    __syncthreads();
    if (tid == 0) {
        atomicAdd(out, wsum[0] + wsum[1] + wsum[2] + wsum[3]);
    }
}

extern "C" void kernel_launch(void* const* d_in, const int* in_sizes, int n_in,
                              void* d_out, int out_size, void* d_ws, size_t ws_size,
                              hipStream_t stream) {
    const float* gt   = (const float*)d_in[0];
    const float* pred = (const float*)d_in[1];
    float* out = (float*)d_out;

    const int B = in_sizes[0] / FPB;     // 16384
    const int ngroups = B / NB;          // 4096

    hipMemsetAsync(out, 0, sizeof(float) * out_size, stream);
    yolo_loss_kernel<<<ngroups, 256, 0, stream>>>(gt, pred, out, ngroups);
}

// Round 3
// 59.565 us; speedup vs baseline: 1.2616x; 1.2616x over previous
//
#include <hip/hip_runtime.h>

#define LAMB_COORD 5.0f
#define LAMB_NOOBJ 0.5f
#define GEPS 1e-7f

// gt/pred: (B=16384, C=30, H=7, W=7) fp32. One thread per cell (b,hw).
// All 60 channel loads issued up-front into registers (max MLP), then compute.
// ncells = 16384*49 = 802816 = 3136 * 256 exactly -> no tail predicate.

__global__ __launch_bounds__(256) void yolo_loss_kernel(
        const float* __restrict__ gt, const float* __restrict__ pred,
        float* __restrict__ out) {
    const int i  = blockIdx.x * 256 + threadIdx.x;
    const int b  = i / 49;
    const int hw = i - b * 49;
    const float* __restrict__ g = gt   + (size_t)b * 1470 + hw;
    const float* __restrict__ p = pred + (size_t)b * 1470 + hw;

    // ---- Issue ALL 60 independent loads before any use ----
    float gv[30], pv[30];
    #pragma unroll
    for (int c = 0; c < 30; ++c) gv[c] = g[c * 49];
    #pragma unroll
    for (int c = 0; c < 30; ++c) pv[c] = p[c * 49];
    __builtin_amdgcn_sched_barrier(0);  // keep loads clustered above compute

    // ---- GIoU(gt box, pred box k) for k=0 (ch 0..3) and k=1 (ch 5..8) ----
    const float gx1 = gv[0], gy1 = gv[1];
    const float gx2 = gv[0] + gv[2], gy2 = gv[1] + gv[3];
    const float ga  = (gx2 - gx1) * (gy2 - gy1);

    float l[2];
    #pragma unroll
    for (int k = 0; k < 2; ++k) {
        const int o = k * 5;
        float px1 = pv[o + 0], py1 = pv[o + 1];
        float px2 = px1 + pv[o + 2], py2 = py1 + pv[o + 3];
        float ix1 = fmaxf(gx1, px1), iy1 = fmaxf(gy1, py1);
        float ix2 = fminf(gx2, px2), iy2 = fminf(gy2, py2);
        float inter = fmaxf(ix2 - ix1, 0.0f) * fmaxf(iy2 - iy1, 0.0f);
        float pa  = (px2 - px1) * (py2 - py1);
        float uni = ga + pa - inter;
        float iou = inter / (uni + GEPS);
        float cx1 = fminf(gx1, px1), cy1 = fminf(gy1, py1);
        float cx2 = fmaxf(gx2, px2), cy2 = fmaxf(gy2, py2);
        float enc = (cx2 - cx1) * (cy2 - cy1);
        l[k] = 1.0f - (iou - (enc - uni) / (enc + GEPS));
    }

    // jnp.argmax first-max tie-break: arg = 1 iff l2 > l1
    float r0, r1;
    if (l[1] > l[0]) { r0 = 0.0f;   r1 = gv[9]; }
    else             { r0 = gv[4];  r1 = 0.0f;  }
    const float appears = fmaxf(r0, r1);

    float s = 0.0f;
    float d;
    d = gv[0] - pv[0]; s += d * d * r0 * LAMB_COORD;
    d = gv[1] - pv[1]; s += d * d * r0 * LAMB_COORD;
    d = gv[5] - pv[5]; s += d * d * r1 * LAMB_COORD;
    d = gv[6] - pv[6]; s += d * d * r1 * LAMB_COORD;
    d = sqrtf(gv[2]) - sqrtf(pv[2]); s += d * d * r0 * LAMB_COORD;
    d = sqrtf(gv[3]) - sqrtf(pv[3]); s += d * d * r0 * LAMB_COORD;
    d = sqrtf(gv[7]) - sqrtf(pv[7]); s += d * d * r1 * LAMB_COORD;
    d = sqrtf(gv[8]) - sqrtf(pv[8]); s += d * d * r1 * LAMB_COORD;
    d = gv[4] - pv[4]; { float d2 = d * d; s += d2 * r0 + d2 * (1.0f - r0) * LAMB_NOOBJ; }
    d = gv[9] - pv[9]; { float d2 = d * d; s += d2 * r1 + d2 * (1.0f - r1) * LAMB_NOOBJ; }

    float cls = 0.0f;
    #pragma unroll
    for (int c = 10; c < 30; ++c) {
        float dc = gv[c] - pv[c];
        cls += dc * dc;
    }
    s += cls * appears;

    // ---- Reduce: 64-lane wave shuffle -> LDS -> one atomic per block ----
    #pragma unroll
    for (int off = 32; off > 0; off >>= 1)
        s += __shfl_down(s, off, 64);

    __shared__ float wsum[4];
    const int lane = threadIdx.x & 63;
    const int wid  = threadIdx.x >> 6;
    if (lane == 0) wsum[wid] = s;
    __syncthreads();
    if (threadIdx.x == 0) {
        atomicAdd(out, wsum[0] + wsum[1] + wsum[2] + wsum[3]);
    }
}

extern "C" void kernel_launch(void* const* d_in, const int* in_sizes, int n_in,
                              void* d_out, int out_size, void* d_ws, size_t ws_size,
                              hipStream_t stream) {
    const float* gt   = (const float*)d_in[0];
    const float* pred = (const float*)d_in[1];
    float* out = (float*)d_out;

    const int B = in_sizes[0] / 1470;    // 16384
    const int ncells = B * 49;           // 802816 = 3136 * 256
    const int grid = ncells / 256;       // 3136

    hipMemsetAsync(out, 0, sizeof(float) * out_size, stream);
    yolo_loss_kernel<<<grid, 256, 0, stream>>>(gt, pred, out);
}